// Round 22
// baseline (255.000 us; speedup 1.0000x reference)
//
#include <hip/hip_runtime.h>

// LSTM: B=1024, S=512, E=H=50, fp32 in/out.
// Grid: 256 blocks x 512 threads (8 waves). Each block owns 4 chains for all 512 steps (1 block/CU).
// Waves 0-5: 2 M-tiles; wave 6: 1; wave 7: x-stager. 13 tiles cover 208 reordered gate rows.
// gates = W_reordered(208x128 fp16 VGPRs) @ [x;h](128x16 fp16 LDS); j=h*4+g reorder ->
// lane (kg,m) acc regs = {i,f,g,o} of cell (chain=m&3, h=4*mt+kg). Compute path = R14 (proven).
// KEY CHANGE vs R14/R21: hipcc emits s_waitcnt vmcnt(0) before every s_barrier (m97), so the
// stager's per-step global_load made EVERY barrier wait a full HBM/L3 round trip (~300-900 cyc)
// -> the hidden ~500 cyc/step stall. Fix: BURST staging every 8th step — ds_write x[t+8..t+15]
// (16-slot ring, 8 KB) from Rb[8][4], then issue all 32 loads x[t+16..t+23]. Only 1 barrier in 8
// pays the vmem drain. Ring lifetime: burst writes slots (t+8..t+15)&15; reads in steps t..t+7
// are slots (t+1..t+8)&15; sole overlap (t+8)&15 is write@t -> read@t+7 (barrier-separated).
// B-operand ds_reads masked m<4 (cols 4-15 zero); act on lanes m<8 via DPP row_shr:4
// (R14-verified); h fp16 2-slot ring; single barrier/step.

typedef __attribute__((ext_vector_type(8))) _Float16 f16x8;  // 8 x fp16 (4 VGPRs) MFMA operand
typedef __attribute__((ext_vector_type(4))) float f32x4;

__device__ __forceinline__ float fast_sigmoid(float z) {
  return __builtin_amdgcn_rcpf(1.0f + __expf(-z));
}
__device__ __forceinline__ float fast_tanh(float z) {
  return 1.0f - 2.0f * __builtin_amdgcn_rcpf(1.0f + __expf(2.0f * z));
}

__global__ __launch_bounds__(512, 1) void lstm_fused(
    const float* __restrict__ xg,     // (1024, 512, 50)
    const float* __restrict__ W_ih,   // (200, 50)
    const float* __restrict__ W_hh,   // (200, 50)
    const float* __restrict__ b_ih,   // (200,)
    const float* __restrict__ b_hh,   // (200,)
    float* __restrict__ out)          // (1024, 1, 50)
{
  constexpr int S = 512, E = 50, H = 50;
  const int tid  = threadIdx.x;
  const int lane = tid & 63;
  const int wv   = tid >> 6;
  const int c0   = blockIdx.x << 2;   // 4 chains per block

  // LDS: xbuf ring[16 slots][2 kt][4 chains][64B] = 8192 B @0
  //      hbuf ring[2 slots][2 kt][4 chains][64B]  = 1024 B @8192
  __shared__ __align__(16) unsigned char lds[9216];
  for (int i = tid; i < 9216 / 4; i += 512) reinterpret_cast<unsigned*>(lds)[i] = 0u;

  const int m  = lane & 15;   // A m-index / D col
  const int kg = lane >> 4;   // k-group of 8; D row-group (h-sub)
  const int tstart = 2 * wv;
  const int ntiles = (wv < 6) ? 2 : ((wv == 6) ? 1 : 0);

  // ---- W fragments: register-stationary fp16 (2 tiles/wave) ----
  f16x8 wfr[2][4];
  f32x4 bias[2];
#pragma unroll
  for (int i = 0; i < 2; ++i) {
    const int  mt    = tstart + i;
    const bool tv    = (i < ntiles);
    const int  j     = mt * 16 + m;     // reordered gate idx = h*4 + g
    const int  hh    = j >> 2, g = j & 3;
    const bool rowok = tv && (hh < H);
#pragma unroll
    for (int kt = 0; kt < 4; ++kt) {
      f16x8 s;
#pragma unroll
      for (int jj = 0; jj < 8; ++jj) {
        const int k = kt * 32 + kg * 8 + jj;
        float w = 0.0f;
        if (rowok) {
          if (k < 50)                  w = W_ih[(g * 50 + hh) * 50 + k];
          else if (k >= 64 && k < 114) w = W_hh[(g * 50 + hh) * 50 + (k - 64)];
        }
        s[jj] = (_Float16)w;
      }
      wfr[i][kt] = s;
    }
    f32x4 bv;
#pragma unroll
    for (int r = 0; r < 4; ++r) {
      const int jr = mt * 16 + kg * 4 + r;
      const int hr = jr >> 2, gr = jr & 3;
      bv[r] = (tv && hr < H) ? (b_ih[gr * 50 + hr] + b_hh[gr * 50 + hr]) : 0.0f;
    }
    bias[i] = bv;
  }

  float cst = 0.0f;   // c state: lane (kg, m<8) owns cell (chain=m&3, h=4*(tstart+(m>>2))+kg)

  // ---- wave 7: x stagers (4 (chain,e) pairs per lane; Rb[8][4] = 8-step burst buffer) ----
  const bool isstg = (wv == 7);
  bool sok[4]; long gb[4]; unsigned la[4];
  float Rb[8][4];
#pragma unroll
  for (int u = 0; u < 4; ++u) {
    const int xs = lane + 64 * u;
    sok[u] = isstg && (xs < 200);
    const int chn = sok[u] ? (xs / 50) : 0;
    const int e   = sok[u] ? (xs - 50 * chn) : 0;
    gb[u] = ((long)(c0 + chn) * S) * E + e;
    la[u] = (unsigned)(((e >> 5) << 8) + (chn << 6) + ((e & 31) << 1));
#pragma unroll
    for (int j = 0; j < 8; ++j) Rb[j][u] = 0.f;
  }

  __syncthreads();   // zeros visible (pads + h0 = 0)

  // prologue: stage x slots 0..7 = x[0..7]; load Rb = x[8..15]
#pragma unroll
  for (int u = 0; u < 4; ++u) {
    if (sok[u]) {
#pragma unroll
      for (int sl = 0; sl < 8; ++sl)
        *reinterpret_cast<_Float16*>(lds + sl * 512 + la[u]) = (_Float16)xg[gb[u] + sl * E];
    }
  }
#pragma unroll
  for (int j = 0; j < 8; ++j) {
#pragma unroll
    for (int u = 0; u < 4; ++u)
      if (sok[u]) Rb[j][u] = xg[gb[u] + (8 + j) * E];
  }
  __syncthreads();   // x slots 0..7 staged

  const unsigned bro = (unsigned)(((lane & 3) << 6) + (kg << 4));
  f16x8 b2{}, b3{}, nb0{}, nb1{};   // persistent; lanes m>=4 stay zero (cols 4-15 dead)

  // ---- prime xcur = bias + W_x @ x[0] (slot 0) ----
  f32x4 xcur[2];
  {
    if (m < 4) {
      nb0 = *reinterpret_cast<const f16x8*>(lds + 0u + bro);
      nb1 = *reinterpret_cast<const f16x8*>(lds + 256u + bro);
    }
#pragma unroll
    for (int i = 0; i < 2; ++i) {
      f32x4 a = bias[i];
      a = __builtin_amdgcn_mfma_f32_16x16x32_f16(wfr[i][0], nb0, a, 0, 0, 0);
      a = __builtin_amdgcn_mfma_f32_16x16x32_f16(wfr[i][1], nb1, a, 0, 0, 0);
      xcur[i] = a;
    }
  }

  for (int t = 0; t < S; ++t) {
    if (ntiles > 0) {
      const unsigned hs = 8192u + (unsigned)(t & 1) * 512u;
      const unsigned xs = ((unsigned)(t + 1) & 15u) * 512u;   // x slot for step t+1
      if (m < 4) {   // only real chain columns read; cols 4-15 stay zero
        b2  = *reinterpret_cast<const f16x8*>(lds + hs + bro);
        b3  = *reinterpret_cast<const f16x8*>(lds + hs + 256u + bro);
        nb0 = *reinterpret_cast<const f16x8*>(lds + xs + bro);
        nb1 = *reinterpret_cast<const f16x8*>(lds + xs + 256u + bro);
      }

      // critical path: h-part, chain depth 2, C-in = precomputed x-part
      f32x4 acc0 = xcur[0];
      acc0 = __builtin_amdgcn_mfma_f32_16x16x32_f16(wfr[0][2], b2, acc0, 0, 0, 0);
      acc0 = __builtin_amdgcn_mfma_f32_16x16x32_f16(wfr[0][3], b3, acc0, 0, 0, 0);
      f32x4 acc1 = xcur[1];
      acc1 = __builtin_amdgcn_mfma_f32_16x16x32_f16(wfr[1][2], b2, acc1, 0, 0, 0);
      acc1 = __builtin_amdgcn_mfma_f32_16x16x32_f16(wfr[1][3], b3, acc1, 0, 0, 0);

      // spread tile-1 gates from lanes m=0..3 to m=4..7 (DPP row_shr:4, R14-verified)
      float gv[4];
#pragma unroll
      for (int r = 0; r < 4; ++r) {
        const int sp = __builtin_amdgcn_update_dpp(
            0, __float_as_int(acc1[r]), 0x114 /*row_shr:4*/, 0xF, 0xF, true);
        gv[r] = (m < 4) ? acc0[r] : __int_as_float(sp);
      }

      // one cell chain per lane: lanes (kg, m<8), tile ti=m>>2, chain m&3
      const int ti = m >> 2;
      const int h  = 4 * (tstart + ti) + kg;
      if ((m < 8) && (ti < ntiles) && (h < H)) {
        const float ig = fast_sigmoid(gv[0]);
        const float fg = fast_sigmoid(gv[1]);
        const float gg = fast_tanh   (gv[2]);
        const float og = fast_sigmoid(gv[3]);
        const float c  = fg * cst + ig * gg;
        cst = c;
        const float hv = og * fast_tanh(c);
        const int ch = m & 3;
        if (t == S - 1) {
          out[(long)(c0 + ch) * H + h] = hv;
        } else {
          *reinterpret_cast<_Float16*>(
              lds + 8192u + (unsigned)((t + 1) & 1) * 512u +
              (unsigned)(((h >> 5) << 8) + (ch << 6) + ((h & 31) << 1))) = (_Float16)hv;
        }
      }

      // off-critical-path: x-part for step t+1
      {
        f32x4 c0v = bias[0];
        c0v = __builtin_amdgcn_mfma_f32_16x16x32_f16(wfr[0][0], nb0, c0v, 0, 0, 0);
        c0v = __builtin_amdgcn_mfma_f32_16x16x32_f16(wfr[0][1], nb1, c0v, 0, 0, 0);
        xcur[0] = c0v;
        f32x4 c1v = bias[1];
        c1v = __builtin_amdgcn_mfma_f32_16x16x32_f16(wfr[1][0], nb0, c1v, 0, 0, 0);
        c1v = __builtin_amdgcn_mfma_f32_16x16x32_f16(wfr[1][1], nb1, c1v, 0, 0, 0);
        xcur[1] = c1v;
      }
    } else if (isstg) {
      if ((t & 7) == 0) {   // burst: 1 barrier in 8 pays the vmem drain
        // ds_write x[t+8..t+15] into ring slots (t+8+j)&15 from Rb (loaded last burst)
#pragma unroll
        for (int j = 0; j < 8; ++j) {
          if (t + 8 + j < S) {
            const unsigned sl = ((unsigned)(t + 8 + j) & 15u) * 512u;
#pragma unroll
            for (int u = 0; u < 4; ++u)
              if (sok[u]) *reinterpret_cast<_Float16*>(lds + sl + la[u]) = (_Float16)Rb[j][u];
          }
        }
        // issue next burst's loads: x[t+16..t+23]
#pragma unroll
        for (int j = 0; j < 8; ++j) {
          if (t + 16 + j < S) {
#pragma unroll
            for (int u = 0; u < 4; ++u)
              if (sok[u]) Rb[j][u] = xg[gb[u] + (long)(t + 16 + j) * E];
          }
        }
      }
    }
    __syncthreads();   // h slot (t+1)&1 and (on burst steps) x slots complete
  }
}

extern "C" void kernel_launch(void* const* d_in, const int* in_sizes, int n_in,
                              void* d_out, int out_size, void* d_ws, size_t ws_size,
                              hipStream_t stream) {
  const float* x    = (const float*)d_in[0];
  const float* W_ih = (const float*)d_in[1];
  const float* W_hh = (const float*)d_in[2];
  const float* b_ih = (const float*)d_in[3];
  const float* b_hh = (const float*)d_in[4];
  float* out = (float*)d_out;
  hipLaunchKernelGGL(lstm_fused, dim3(256), dim3(512), 0, stream,
                     x, W_ih, W_hh, b_ih, b_hh, out);
}

// Round 23
// 233.966 us; speedup vs baseline: 1.0899x; 1.0899x over previous
//
#include <hip/hip_runtime.h>

// LSTM: B=1024, S=512, E=H=50, fp32 in/out.
// Grid: 256 blocks x 256 threads (4 waves, 1 wave/SIMD). Each block owns 4 chains, all 512 steps.
// R22 post-mortem: burst staging refuted the vmem-drain theory (worse). R7..R21 show issue cuts
// don't move the ~940 cyc/step wall; the untested knob is the barrier itself: all ~200us variants
// synced 8 waves with 2 same-phase waves/SIMD (no mutual hiding, max-of-8 skew, 8 drains).
// This variant: SAME total work, 4-wave barrier, 1 wave/SIMD (no same-phase SIMD contention).
// 13 tiles split {4,3,3,3} (R17-validated); per-wave 13-16 MFMA/step on its own SIMD.
// gates = W_reordered(208x128 fp16 VGPRs) @ [x;h](128x16 fp16 LDS); j=h*4+g reorder ->
// lane (kg,m) acc_i regs = {i,f,g,o} of cell (chain=m&3, h=4*(tstart+i)+kg).
// B-operand ds_reads masked m<4 (cols 4-15 zero). Tile-i gates spread to lanes m=4i..4i+3 via
// DPP row_shr:4/8/12 (verified: lane reads lane-N) + 2-level select; ONE 10-trans chain/lane.
// x staging: threads 56..255 own one (chain,e) pair; 4-slot ring; R17-proven 4-reg rotation
// (step(t,P,Q): issue Q<-x[t+4] at top, write P=x[t+2] at bottom). Single barrier/step.

typedef __attribute__((ext_vector_type(8))) _Float16 f16x8;  // 8 x fp16 (4 VGPRs) MFMA operand
typedef __attribute__((ext_vector_type(4))) float f32x4;

__device__ __forceinline__ float fast_sigmoid(float z) {
  return __builtin_amdgcn_rcpf(1.0f + __expf(-z));
}
__device__ __forceinline__ float fast_tanh(float z) {
  return 1.0f - 2.0f * __builtin_amdgcn_rcpf(1.0f + __expf(2.0f * z));
}

__global__ __launch_bounds__(256, 1) void lstm_fused(
    const float* __restrict__ xg,     // (1024, 512, 50)
    const float* __restrict__ W_ih,   // (200, 50)
    const float* __restrict__ W_hh,   // (200, 50)
    const float* __restrict__ b_ih,   // (200,)
    const float* __restrict__ b_hh,   // (200,)
    float* __restrict__ out)          // (1024, 1, 50)
{
  constexpr int S = 512, E = 50, H = 50;
  const int tid  = threadIdx.x;
  const int lane = tid & 63;
  const int wv   = tid >> 6;          // 0..3
  const int c0   = blockIdx.x << 2;   // 4 chains per block

  // LDS: xbuf ring[4 slots][2 kt][4 chains][64B] = 2048 B @0
  //      hbuf ring[2 slots][2 kt][4 chains][64B] = 1024 B @2048
  __shared__ __align__(16) unsigned char lds[3072];
  for (int i = tid; i < 3072 / 4; i += 256) reinterpret_cast<unsigned*>(lds)[i] = 0u;

  const int m  = lane & 15;   // A m-index / D col
  const int kg = lane >> 4;   // k-group of 8; D row-group (h-sub)
  const int tstart = (wv == 0) ? 0 : (4 + 3 * (wv - 1));   // {0,4,7,10}
  const int ntiles = (wv == 0) ? 4 : 3;

  // ---- W fragments: register-stationary fp16 (up to 4 tiles/wave) ----
  f16x8 wfr[4][4];
  f32x4 bias[4];
#pragma unroll
  for (int i = 0; i < 4; ++i) {
    const int  mt    = tstart + i;
    const bool tv    = (i < ntiles);
    const int  j     = mt * 16 + m;     // reordered gate idx = h*4 + g
    const int  hh    = j >> 2, g = j & 3;
    const bool rowok = tv && (hh < H);
#pragma unroll
    for (int kt = 0; kt < 4; ++kt) {
      f16x8 s;
#pragma unroll
      for (int jj = 0; jj < 8; ++jj) {
        const int k = kt * 32 + kg * 8 + jj;
        float w = 0.0f;
        if (rowok) {
          if (k < 50)                  w = W_ih[(g * 50 + hh) * 50 + k];
          else if (k >= 64 && k < 114) w = W_hh[(g * 50 + hh) * 50 + (k - 64)];
        }
        s[jj] = (_Float16)w;
      }
      wfr[i][kt] = s;
    }
    f32x4 bv;
#pragma unroll
    for (int r = 0; r < 4; ++r) {
      const int jr = mt * 16 + kg * 4 + r;
      const int hr = jr >> 2, gr = jr & 3;
      bv[r] = (tv && hr < H) ? (b_ih[gr * 50 + hr] + b_hh[gr * 50 + hr]) : 0.0f;
    }
    bias[i] = bv;
  }

  float cst = 0.0f;   // c state: lane (kg, m<4*ntiles) owns cell (chain=m&3, h=4*(tstart+(m>>2))+kg)

  // ---- x staging: threads 56..255 own one (chain,e) pair each (200 pairs) ----
  const int  s     = tid - 56;
  const bool sok   = (s >= 0) && (s < 200);
  const int  schn  = sok ? (s / 50) : 0;
  const int  se    = sok ? (s - 50 * schn) : 0;
  const long gb    = ((long)(c0 + schn) * S) * E + se;
  const unsigned la = (unsigned)(((se >> 5) << 8) + (schn << 6) + ((se & 31) << 1));
  float A = 0.f, B = 0.f, C = 0.f, D = 0.f;

  __syncthreads();   // zeros visible (pads + h0 = 0)

  if (sok) {
    *reinterpret_cast<_Float16*>(lds + 0 * 512 + la) = (_Float16)xg[gb + 0 * E];
    *reinterpret_cast<_Float16*>(lds + 1 * 512 + la) = (_Float16)xg[gb + 1 * E];
    A = xg[gb + 2 * E];
    B = xg[gb + 3 * E];
  }
  __syncthreads();   // x slots 0,1 staged

  const unsigned bro = (unsigned)(((lane & 3) << 6) + (kg << 4));

  // B-operand registers: persistent, zero for lanes m>=4 (masked loads keep cols 4-15 zero)
  f16x8 b2{}, b3{}, nb0{}, nb1{};

  // ---- prime xcur = bias + W_x @ x[0] (slot 0) ----
  f32x4 xcur[4];
  {
    if (m < 4) {
      nb0 = *reinterpret_cast<const f16x8*>(lds + 0u + bro);
      nb1 = *reinterpret_cast<const f16x8*>(lds + 256u + bro);
    }
#pragma unroll
    for (int i = 0; i < 4; ++i) {
      if (i < ntiles) {
        f32x4 a = bias[i];
        a = __builtin_amdgcn_mfma_f32_16x16x32_f16(wfr[i][0], nb0, a, 0, 0, 0);
        a = __builtin_amdgcn_mfma_f32_16x16x32_f16(wfr[i][1], nb1, a, 0, 0, 0);
        xcur[i] = a;
      } else {
        xcur[i] = bias[i];
      }
    }
  }

  auto step = [&](int t, float& P, float& Q) {
    // issue x[t+4] early into Q (the register written as x[(t+2)+2] two steps later)
    if (sok && (t + 4) < S) Q = xg[gb + (long)(t + 4) * E];

    const unsigned hs = 2048u + (unsigned)(t & 1) * 512u;
    const unsigned xs = (unsigned)((t + 1) & 3) * 512u;
    if (m < 4) {   // only real chain columns read; cols 4-15 stay zero
      b2  = *reinterpret_cast<const f16x8*>(lds + hs + bro);
      b3  = *reinterpret_cast<const f16x8*>(lds + hs + 256u + bro);
      nb0 = *reinterpret_cast<const f16x8*>(lds + xs + bro);
      nb1 = *reinterpret_cast<const f16x8*>(lds + xs + 256u + bro);
    }

    // critical path: h-part, chain depth 2, C-in = precomputed x-part
    f32x4 acc[4];
#pragma unroll
    for (int i = 0; i < 4; ++i) {
      if (i < ntiles) {
        f32x4 a = xcur[i];
        a = __builtin_amdgcn_mfma_f32_16x16x32_f16(wfr[i][2], b2, a, 0, 0, 0);
        a = __builtin_amdgcn_mfma_f32_16x16x32_f16(wfr[i][3], b3, a, 0, 0, 0);
        acc[i] = a;
      } else {
        acc[i] = xcur[i];
      }
    }

    // spread tile-i gates (lanes m=0..3) to lanes m=4i..4i+3 (row_shr:4i; lane reads lane-N)
    float gv[4];
#pragma unroll
    for (int r = 0; r < 4; ++r) {
      const int s1 = __builtin_amdgcn_update_dpp(
          0, __float_as_int(acc[1][r]), 0x114 /*row_shr:4*/, 0xF, 0xF, true);
      const int s2 = __builtin_amdgcn_update_dpp(
          0, __float_as_int(acc[2][r]), 0x118 /*row_shr:8*/, 0xF, 0xF, true);
      const int s3 = __builtin_amdgcn_update_dpp(
          0, __float_as_int(acc[3][r]), 0x11C /*row_shr:12*/, 0xF, 0xF, true);
      const float lo = (m & 4) ? __int_as_float(s1) : acc[0][r];
      const float hi = (m & 4) ? __int_as_float(s3) : __int_as_float(s2);
      gv[r] = (m & 8) ? hi : lo;
    }

    // one cell chain per lane: lanes (kg, m<4*ntiles), tile ti=m>>2, chain m&3
    const int ti = m >> 2;
    const int h  = 4 * (tstart + ti) + kg;
    if ((ti < ntiles) && (h < H)) {
      const float ig = fast_sigmoid(gv[0]);
      const float fg = fast_sigmoid(gv[1]);
      const float gg = fast_tanh   (gv[2]);
      const float og = fast_sigmoid(gv[3]);
      const float c  = fg * cst + ig * gg;
      cst = c;
      const float hv = og * fast_tanh(c);
      const int ch = m & 3;
      if (t == S - 1) {
        out[(long)(c0 + ch) * H + h] = hv;
      } else {
        *reinterpret_cast<_Float16*>(
            lds + 2048u + (unsigned)((t + 1) & 1) * 512u +
            (unsigned)(((h >> 5) << 8) + (ch << 6) + ((h & 31) << 1))) = (_Float16)hv;
      }
    }

    // off-critical-path: x-part for step t+1
#pragma unroll
    for (int i = 0; i < 4; ++i) {
      if (i < ntiles) {
        f32x4 a = bias[i];
        a = __builtin_amdgcn_mfma_f32_16x16x32_f16(wfr[i][0], nb0, a, 0, 0, 0);
        a = __builtin_amdgcn_mfma_f32_16x16x32_f16(wfr[i][1], nb1, a, 0, 0, 0);
        xcur[i] = a;
      }
    }

    // write x[t+2] (issued 2 steps ago into P) into its ring slot
    if (sok && (t + 2) < S) {
      *reinterpret_cast<_Float16*>(lds + (unsigned)((t + 2) & 3) * 512u + la) = (_Float16)P;
    }
    __syncthreads();   // h slot (t+1)&1 and x slot (t+2)&3 complete
  };

  for (int t = 0; t < S; t += 4) {
    step(t + 0, A, C);
    step(t + 1, B, D);
    step(t + 2, C, A);
    step(t + 3, D, B);
  }
}

extern "C" void kernel_launch(void* const* d_in, const int* in_sizes, int n_in,
                              void* d_out, int out_size, void* d_ws, size_t ws_size,
                              hipStream_t stream) {
  const float* x    = (const float*)d_in[0];
  const float* W_ih = (const float*)d_in[1];
  const float* W_hh = (const float*)d_in[2];
  const float* b_ih = (const float*)d_in[3];
  const float* b_hh = (const float*)d_in[4];
  float* out = (float*)d_out;
  hipLaunchKernelGGL(lstm_fused, dim3(256), dim3(256), 0, stream,
                     x, W_ih, W_hh, b_ih, b_hh, out);
}

// Round 24
// 200.235 us; speedup vs baseline: 1.2735x; 1.1685x over previous
//
#include <hip/hip_runtime.h>

// LSTM: B=1024, S=512, E=H=50, fp32 in/out.
// Grid: 256 blocks x 512 threads (8 waves). Each block owns 4 chains for all 512 steps (1 block/CU).
// == R14 structure verbatim (best verified: 200.4 us, absmax 1.95e-3) with ONE change:
// the per-step __syncthreads() is replaced by  s_waitcnt lgkmcnt(0) + raw s_barrier.
// Rationale: hipcc emits s_waitcnt vmcnt(0) lgkmcnt(0) before s_barrier (guide m97), so the
// stager wave's in-flight global x-loads make EVERY one of the 512 barriers wait an HBM round
// trip for ALL 8 waves. Cross-wave communication here is LDS-only (h-ring, x-ring), so
// lgkmcnt(0) alone is sufficient for visibility; the x-load->ds_write dependency carries its own
// compiler-inserted vmcnt wait at the ds_write, off the barrier path. (T3/T4: never drain
// vmcnt(0) at a barrier.) R22's burst test did NOT refute this theory - it added a 32-load
// mega-drain at its burst barrier.
// Waves 0-5: 2 M-tiles; wave 6: 1 M-tile; wave 7: x-stager. 13 tiles cover 208 gate rows.
// gates(16x16 tiles) = W_reordered(208x128, fp16 in VGPRs) @ [x;h] (128x16, fp16 in LDS).
// Gate reorder j = h*4 + g -> lane (kg,m)'s acc regs = {i,f,g,o} of cell (chain=m&3, h=4*mt+kg).
// B-operand ds_reads masked m<4 (cols 4-15 zero). Tile-1 gates spread to lanes m=4..7 via DPP
// row_shr:4; each active lane runs ONE 10-trans cell chain. x-part of t+1 prefetched via xcur.
// Stager: 4 (chain,e) pairs/lane, 4-slot ring, R0/R1 parity regs, write-then-reload.

typedef __attribute__((ext_vector_type(8))) _Float16 f16x8;  // 8 x fp16 (4 VGPRs) MFMA operand
typedef __attribute__((ext_vector_type(4))) float f32x4;

__device__ __forceinline__ float fast_sigmoid(float z) {
  return __builtin_amdgcn_rcpf(1.0f + __expf(-z));
}
__device__ __forceinline__ float fast_tanh(float z) {
  return 1.0f - 2.0f * __builtin_amdgcn_rcpf(1.0f + __expf(2.0f * z));
}

// LDS-only barrier: ds_writes complete (lgkmcnt) -> visible to all waves after s_barrier.
// Deliberately NO vmcnt drain (no cross-wave global communication exists in this kernel).
__device__ __forceinline__ void lds_barrier() {
  asm volatile("s_waitcnt lgkmcnt(0)" ::: "memory");
  __builtin_amdgcn_s_barrier();
}

__global__ __launch_bounds__(512, 1) void lstm_fused(
    const float* __restrict__ xg,     // (1024, 512, 50)
    const float* __restrict__ W_ih,   // (200, 50)
    const float* __restrict__ W_hh,   // (200, 50)
    const float* __restrict__ b_ih,   // (200,)
    const float* __restrict__ b_hh,   // (200,)
    float* __restrict__ out)          // (1024, 1, 50)
{
  constexpr int S = 512, E = 50, H = 50;
  const int tid  = threadIdx.x;
  const int lane = tid & 63;
  const int wv   = tid >> 6;
  const int c0   = blockIdx.x << 2;   // 4 chains per block

  // LDS: xbuf ring[4 slots][2 kt][4 chains][64B] = 2048 B @0
  //      hbuf ring[2 slots][2 kt][4 chains][64B] = 1024 B @2048
  __shared__ __align__(16) unsigned char lds[3072];
  for (int i = tid; i < 3072 / 4; i += 512) reinterpret_cast<unsigned*>(lds)[i] = 0u;

  const int m  = lane & 15;   // A m-index / D col
  const int kg = lane >> 4;   // k-group of 8; D row-group (h-sub)
  const int tstart = 2 * wv;
  const int ntiles = (wv < 6) ? 2 : ((wv == 6) ? 1 : 0);

  // ---- W fragments: register-stationary fp16 (2 tiles/wave) ----
  f16x8 wfr[2][4];
  f32x4 bias[2];
#pragma unroll
  for (int i = 0; i < 2; ++i) {
    const int  mt    = tstart + i;
    const bool tv    = (i < ntiles);
    const int  j     = mt * 16 + m;     // reordered gate idx = h*4 + g
    const int  hh    = j >> 2, g = j & 3;
    const bool rowok = tv && (hh < H);
#pragma unroll
    for (int kt = 0; kt < 4; ++kt) {
      f16x8 s;
#pragma unroll
      for (int jj = 0; jj < 8; ++jj) {
        const int k = kt * 32 + kg * 8 + jj;
        float w = 0.0f;
        if (rowok) {
          if (k < 50)                  w = W_ih[(g * 50 + hh) * 50 + k];
          else if (k >= 64 && k < 114) w = W_hh[(g * 50 + hh) * 50 + (k - 64)];
        }
        s[jj] = (_Float16)w;
      }
      wfr[i][kt] = s;
    }
    f32x4 bv;
#pragma unroll
    for (int r = 0; r < 4; ++r) {
      const int jr = mt * 16 + kg * 4 + r;
      const int hr = jr >> 2, gr = jr & 3;
      bv[r] = (tv && hr < H) ? (b_ih[gr * 50 + hr] + b_hh[gr * 50 + hr]) : 0.0f;
    }
    bias[i] = bv;
  }

  float cst = 0.0f;   // c state: lane (kg, m<8) owns cell (chain=m&3, h=4*(tstart+(m>>2))+kg)

  // ---- wave 7: x stagers (4 (chain,e) slots per lane) ----
  const bool isstg = (wv == 7);
  bool sok[4]; long gb[4]; unsigned la[4];
  float R0[4], R1[4];                  // R0 used at even t, R1 at odd t
#pragma unroll
  for (int u = 0; u < 4; ++u) {
    const int xs = lane + 64 * u;
    sok[u] = isstg && (xs < 200);
    const int chn = sok[u] ? (xs / 50) : 0;
    const int e   = sok[u] ? (xs - 50 * chn) : 0;
    gb[u] = ((long)(c0 + chn) * S) * E + e;
    la[u] = (unsigned)(((e >> 5) << 8) + (chn << 6) + ((e & 31) << 1));
    R0[u] = 0.f; R1[u] = 0.f;
  }

  __syncthreads();   // zeros visible (pads + h0 = 0)

  // prime x slots 0,1; load x[2],x[3] into stage regs
#pragma unroll
  for (int u = 0; u < 4; ++u) {
    if (sok[u]) {
      *reinterpret_cast<_Float16*>(lds + 0 * 512 + la[u]) = (_Float16)xg[gb[u] + 0 * E];
      *reinterpret_cast<_Float16*>(lds + 1 * 512 + la[u]) = (_Float16)xg[gb[u] + 1 * E];
    }
  }
#pragma unroll
  for (int u = 0; u < 4; ++u) {
    if (sok[u]) { R0[u] = xg[gb[u] + 2 * E]; R1[u] = xg[gb[u] + 3 * E]; }
  }
  __syncthreads();   // x slots 0,1 staged

  const unsigned bro = (unsigned)(((lane & 3) << 6) + (kg << 4));

  // B-operand registers: persistent, zero for lanes m>=4 (masked loads keep cols 4-15 zero)
  f16x8 b2{}, b3{}, nb0{}, nb1{};

  // ---- prime xcur = bias + W_x @ x[0] (slot 0) ----
  f32x4 xcur[2];
  {
    if (m < 4) {
      nb0 = *reinterpret_cast<const f16x8*>(lds + 0u + bro);
      nb1 = *reinterpret_cast<const f16x8*>(lds + 256u + bro);
    }
#pragma unroll
    for (int i = 0; i < 2; ++i) {
      f32x4 a = bias[i];
      a = __builtin_amdgcn_mfma_f32_16x16x32_f16(wfr[i][0], nb0, a, 0, 0, 0);
      a = __builtin_amdgcn_mfma_f32_16x16x32_f16(wfr[i][1], nb1, a, 0, 0, 0);
      xcur[i] = a;
    }
  }

  auto step = [&](int t, float (&P)[4], float (&Q)[4]) {
    if (ntiles > 0) {
      const unsigned hs = 2048u + (unsigned)(t & 1) * 512u;
      const unsigned xs = (unsigned)((t + 1) & 3) * 512u;
      if (m < 4) {   // only real chain columns read; cols 4-15 stay zero
        b2  = *reinterpret_cast<const f16x8*>(lds + hs + bro);
        b3  = *reinterpret_cast<const f16x8*>(lds + hs + 256u + bro);
        nb0 = *reinterpret_cast<const f16x8*>(lds + xs + bro);
        nb1 = *reinterpret_cast<const f16x8*>(lds + xs + 256u + bro);
      }

      // critical path: h-part, chain depth 2, C-in = precomputed x-part
      f32x4 acc0 = xcur[0];
      acc0 = __builtin_amdgcn_mfma_f32_16x16x32_f16(wfr[0][2], b2, acc0, 0, 0, 0);
      acc0 = __builtin_amdgcn_mfma_f32_16x16x32_f16(wfr[0][3], b3, acc0, 0, 0, 0);
      f32x4 acc1 = xcur[1];
      acc1 = __builtin_amdgcn_mfma_f32_16x16x32_f16(wfr[1][2], b2, acc1, 0, 0, 0);
      acc1 = __builtin_amdgcn_mfma_f32_16x16x32_f16(wfr[1][3], b3, acc1, 0, 0, 0);

      // spread tile-1 gates from lanes m=0..3 to m=4..7 (DPP row_shr:4, verified)
      float gv[4];
#pragma unroll
      for (int r = 0; r < 4; ++r) {
        const int sp = __builtin_amdgcn_update_dpp(
            0, __float_as_int(acc1[r]), 0x114 /*row_shr:4*/, 0xF, 0xF, true);
        gv[r] = (m < 4) ? acc0[r] : __int_as_float(sp);
      }

      // one cell chain per lane: lanes (kg, m<8), tile ti=m>>2, chain m&3
      const int ti = m >> 2;
      const int h  = 4 * (tstart + ti) + kg;
      if ((m < 8) && (ti < ntiles) && (h < H)) {
        const float ig = fast_sigmoid(gv[0]);
        const float fg = fast_sigmoid(gv[1]);
        const float gg = fast_tanh   (gv[2]);
        const float og = fast_sigmoid(gv[3]);
        const float c  = fg * cst + ig * gg;
        cst = c;
        const float hv = og * fast_tanh(c);
        const int ch = m & 3;
        if (t == S - 1) {
          out[(long)(c0 + ch) * H + h] = hv;
        } else {
          *reinterpret_cast<_Float16*>(
              lds + 2048u + (unsigned)((t + 1) & 1) * 512u +
              (unsigned)(((h >> 5) << 8) + (ch << 6) + ((h & 31) << 1))) = (_Float16)hv;
        }
      }

      // off-critical-path: x-part for step t+1
      {
        f32x4 c0v = bias[0];
        c0v = __builtin_amdgcn_mfma_f32_16x16x32_f16(wfr[0][0], nb0, c0v, 0, 0, 0);
        c0v = __builtin_amdgcn_mfma_f32_16x16x32_f16(wfr[0][1], nb1, c0v, 0, 0, 0);
        xcur[0] = c0v;
        f32x4 c1v = bias[1];
        c1v = __builtin_amdgcn_mfma_f32_16x16x32_f16(wfr[1][0], nb0, c1v, 0, 0, 0);
        c1v = __builtin_amdgcn_mfma_f32_16x16x32_f16(wfr[1][1], nb1, c1v, 0, 0, 0);
        xcur[1] = c1v;
      }
    } else if (isstg) {
      if (t + 2 < S) {
        // write x[t+2] (loaded 2 steps ago); the load->store dependency carries its own
        // compiler-inserted vmcnt wait, off the barrier path.
        const unsigned sl = (unsigned)((t + 2) & 3) * 512u;
#pragma unroll
        for (int u = 0; u < 4; ++u)
          if (sok[u]) *reinterpret_cast<_Float16*>(lds + sl + la[u]) = (_Float16)P[u];
        if (t + 4 < S) {
#pragma unroll
          for (int u = 0; u < 4; ++u)
            if (sok[u]) P[u] = xg[gb[u] + (long)(t + 4) * E];
        }
      }
    }
    lds_barrier();   // lgkmcnt(0)+s_barrier: h slot (t+1)&1 and x slot (t+2)&3 visible; NO vmcnt drain
  };

  for (int t = 0; t < S; t += 2) {
    step(t, R0, R1);
    step(t + 1, R1, R0);
  }
}

extern "C" void kernel_launch(void* const* d_in, const int* in_sizes, int n_in,
                              void* d_out, int out_size, void* d_ws, size_t ws_size,
                              hipStream_t stream) {
  const float* x    = (const float*)d_in[0];
  const float* W_ih = (const float*)d_in[1];
  const float* W_hh = (const float*)d_in[2];
  const float* b_ih = (const float*)d_in[3];
  const float* b_hh = (const float*)d_in[4];
  float* out = (float*)d_out;
  hipLaunchKernelGGL(lstm_fused, dim3(256), dim3(512), 0, stream,
                     x, W_ih, W_hh, b_ih, b_hh, out);
}